// Round 5
// baseline (307.843 us; speedup 1.0000x reference)
//
#include <hip/hip_runtime.h>

#define NN 64
#define IND 256
#define NH 8
#define OD 32

typedef __attribute__((ext_vector_type(8))) short bf16x8;
typedef __attribute__((ext_vector_type(4))) float f32x4;

__device__ __forceinline__ unsigned f2bf(float f) {
  unsigned u = __float_as_uint(f);
  return (u + (((u >> 16) & 1u) + 0x7fffu)) >> 16;  // RNE
}

// V[h][k] = sum_d W[k, h*32+d] * Watt[h, d]   (8 x 256)
__global__ __launch_bounds__(256) void precompute_v(
    const float* __restrict__ W, const float* __restrict__ Watt, float* __restrict__ V) {
  int tid = blockIdx.x * 256 + threadIdx.x;
  if (tid >= IND * NH) return;
  int h = tid >> 8, k = tid & 255;
  float acc = 0.f;
#pragma unroll
  for (int d = 0; d < OD; ++d) acc += W[k * 256 + h * OD + d] * Watt[h * OD + d];
  V[h * 256 + k] = acc;
}

// LDS layout (bytes):
//  [0,     33792)  s bf16 [64][264] (row = 132 words = 33 granules)
//                  overlay post-barrier-1: yp float [32][260]  (33280 B)
//  [33792, 38016)  v bf16 [8][264]  (4224 B)
//                  overlay post-barrier-1: alpha float [64][8] (2048 B)
//                  overlay post-barrier-3: pp float [4][256]   (4096 B)
//  [38016, 40320)  e float [64][9]  (2304 B)
#define V_OFF 33792
#define E_OFF (V_OFF + 4224)
#define SMEM_BYTES (E_OFF + 2304)

#define STAGE_V()                                                     \
  {                                                                   \
    const float4* V4 = (const float4*)V;                              \
    _Pragma("unroll") for (int r = 0; r < 8; ++r) {                   \
      float4 vv = V4[r * 64 + l];                                     \
      unsigned p0 = f2bf(vv.x) | (f2bf(vv.y) << 16);                  \
      unsigned p1 = f2bf(vv.z) | (f2bf(vv.w) << 16);                  \
      *(uint2*)(v_pk + r * 132 + 2 * l) = make_uint2(p0, p1);         \
    }                                                                 \
  }

// pack s = xi + xj (xj from regs, xi streamed in 2 chunks of 8)
#define PACK_S(XI4, XJ)                                               \
  _Pragma("unroll") for (int c = 0; c < 2; ++c) {                     \
    float4 xi[8];                                                     \
    _Pragma("unroll") for (int i = 0; i < 8; ++i)                     \
        xi[i] = (XI4)[(c * 8 + i) * 64 + l];                          \
    _Pragma("unroll") for (int i = 0; i < 8; ++i) {                   \
      int r = c * 8 + i;                                              \
      float4 a = (XJ)[r], ci = xi[i];                                 \
      unsigned p0 = f2bf(a.x + ci.x) | (f2bf(a.y + ci.y) << 16);      \
      unsigned p1 = f2bf(a.z + ci.z) | (f2bf(a.w + ci.w) << 16);      \
      *(uint2*)(s_pk + (w * 16 + r) * 132 + l * 2) = make_uint2(p0, p1); \
    }                                                                 \
  }

// NOTE: no min-waves bound. Measured: (256,3)->84 VGPR cap, (256,4)->64 cap
// -> catastrophic spill. Plain bounds -> ~104-120 VGPR, no spill; LDS=40448
// caps residency at 4 blocks/CU regardless.
__global__ __launch_bounds__(256) void gat_fused(
    const float* __restrict__ Xi, const float* __restrict__ Xj,
    const float* __restrict__ W, const float* __restrict__ V,
    float* __restrict__ out, int nB) {
  __shared__ __align__(16) unsigned char smem[SMEM_BYTES];
  unsigned* s_pk = (unsigned*)smem;
  unsigned* v_pk = (unsigned*)(smem + V_OFF);
  float* e_f = (float*)(smem + E_OFF);
  float* alpha_f = (float*)(smem + V_OFF);  // overlay: valid after barrier 1
  float* pp_f = (float*)(smem + V_OFF);     // overlay: valid after barrier 3
  float* yp_f = (float*)smem;               // overlay: valid after barrier 1

  const int t = threadIdx.x;
  const int w = t >> 6, l = t & 63;
  const int g = l >> 3, h = l & 7;

  const int b0 = blockIdx.x;
  const int b1 = blockIdx.x + gridDim.x;
  const bool has2 = (b1 < nB);

  const float4* Xi4a = (const float4*)Xi + (size_t)b0 * (NN * IND / 4) + w * 1024;
  const float4* Xj4a = (const float4*)Xj + (size_t)b0 * (NN * IND / 4) + w * 1024;
  const float4* Xi4b = (const float4*)Xi + (size_t)b1 * (NN * IND / 4) + w * 1024;
  const float4* Xj4b = (const float4*)Xj + (size_t)b1 * (NN * IND / 4) + w * 1024;

  float4 xjA[16], xjB[16];

  STAGE_V();
#pragma unroll
  for (int i = 0; i < 16; ++i) xjA[i] = Xj4a[i * 64 + l];
  PACK_S(Xi4a, xjA);

  // ---------------- iteration 0 (b0), prefetches b1 ----------------
  {
    // Phase B (MFMA): e = s . V^T. A-frag lane(q=l>>4, r16=l&15) reads
    // s[16w+r16][32*step+8q..+7]; B-frag same k-map from V row (r16&7).
    // Wave-local (own s rows): no barrier before B.
    {
      const int r16 = l & 15, q = l >> 4;
      const unsigned* arow = s_pk + (w * 16 + r16) * 132;
      const unsigned* brow = v_pk + (r16 & 7) * 132;
      f32x4 acc = {0.f, 0.f, 0.f, 0.f};
#pragma unroll
      for (int step = 0; step < 8; ++step) {
        bf16x8 af = *(const bf16x8*)(arow + step * 16 + q * 4);
        bf16x8 bfv = *(const bf16x8*)(brow + step * 16 + q * 4);
        acc = __builtin_amdgcn_mfma_f32_16x16x32_bf16(af, bfv, acc, 0, 0, 0);
      }
      if (r16 < 8) {
#pragma unroll
        for (int j = 0; j < 4; ++j) {
          float ev = acc[j];
          ev = ev >= 0.f ? ev : 0.2f * ev;
          e_f[(w * 16 + q * 4 + j) * 9 + r16] = ev;  // row=(l>>4)*4+j, col=l&15
        }
      }
    }
    __syncthreads();  // barrier 1: e complete; s,v dead

    float m = -3.4e38f;
#pragma unroll
    for (int q = 0; q < 8; ++q) m = fmaxf(m, e_f[(g * 8 + q) * 9 + h]);
    m = fmaxf(m, __shfl_xor(m, 8, 64));
    m = fmaxf(m, __shfl_xor(m, 16, 64));
    m = fmaxf(m, __shfl_xor(m, 32, 64));
    float ssum = 0.f;
#pragma unroll
    for (int q = 0; q < 8; ++q) ssum += __expf(e_f[(g * 8 + q) * 9 + h] - m);
    ssum += __shfl_xor(ssum, 8, 64);
    ssum += __shfl_xor(ssum, 16, 64);
    ssum += __shfl_xor(ssum, 32, 64);
    float rinv = 1.f / ssum;
#pragma unroll
    for (int pp = 0; pp < 2; ++pp) {
      int n = w * 16 + g + 8 * pp;
      alpha_f[n * 8 + h] = __expf(e_f[n * 9 + h] - m) * rinv;
    }

    // Phase C from register xjA; wave-local alpha (no barrier needed).
    float4 acc4[8];
#pragma unroll
    for (int hh = 0; hh < 8; ++hh) acc4[hh] = make_float4(0.f, 0.f, 0.f, 0.f);
#pragma unroll
    for (int i = 0; i < 16; ++i) {
      int n = w * 16 + i;
      float4 a0 = *(const float4*)(alpha_f + n * 8);
      float4 a1 = *(const float4*)(alpha_f + n * 8 + 4);
      float al[8] = {a0.x, a0.y, a0.z, a0.w, a1.x, a1.y, a1.z, a1.w};
      float4 x = xjA[i];
#pragma unroll
      for (int hh = 0; hh < 8; ++hh) {
        acc4[hh].x += al[hh] * x.x;
        acc4[hh].y += al[hh] * x.y;
        acc4[hh].z += al[hh] * x.z;
        acc4[hh].w += al[hh] * x.w;
      }
    }

    // xjA dead: prefetch b1's xj into the freed registers NOW, so its 64KB
    // streams under this b's pre-reduce/epilogue. sched_barrier pins issue.
    if (has2) {
#pragma unroll
      for (int i = 0; i < 16; ++i) xjB[i] = Xj4b[i * 64 + l];
      __builtin_amdgcn_sched_barrier(0);
    }

#pragma unroll
    for (int hh = 0; hh < 8; ++hh)
      *(float4*)(yp_f + (w * 8 + hh) * 260 + 4 * l) = acc4[hh];
    __syncthreads();  // barrier 2: yp complete

    // pre-reduce 32 partial rows -> 8 rows, b128, in place
#pragma unroll
    for (int c = 0; c < 2; ++c) {
      int id = t + c * 256;
      int row = id >> 6, col = (id & 63) * 4;
      float* p = yp_f + row * 260 + col;
      float4 s0 = *(float4*)p;
      float4 s1 = *(float4*)(p + 2080);
      float4 s2 = *(float4*)(p + 4160);
      float4 s3 = *(float4*)(p + 6240);
      s0.x += s1.x + s2.x + s3.x;
      s0.y += s1.y + s2.y + s3.y;
      s0.z += s1.z + s2.z + s3.z;
      s0.w += s1.w + s2.w + s3.w;
      *(float4*)p = s0;
    }
    __syncthreads();  // barrier 3: y rows 0-7 final

    {
      const float* ypb = yp_f + g * 260;
      const float4* W4 = (const float4*)W;
      float4 acc = make_float4(0.f, 0.f, 0.f, 0.f);
      int k0 = w * 64;
#pragma unroll 8
      for (int kc = 0; kc < 16; ++kc) {
        int k = k0 + kc * 4;
        float4 yv = *(const float4*)(ypb + k);
        float4 w0 = W4[(k + 0) * 64 + l];
        float4 w1 = W4[(k + 1) * 64 + l];
        float4 w2 = W4[(k + 2) * 64 + l];
        float4 w3 = W4[(k + 3) * 64 + l];
        acc.x += yv.x * w0.x + yv.y * w1.x + yv.z * w2.x + yv.w * w3.x;
        acc.y += yv.x * w0.y + yv.y * w1.y + yv.z * w2.y + yv.w * w3.y;
        acc.z += yv.x * w0.z + yv.y * w1.z + yv.z * w2.z + yv.w * w3.z;
        acc.w += yv.x * w0.w + yv.y * w1.w + yv.z * w2.w + yv.w * w3.w;
      }
      *(float4*)(pp_f + w * 256 + 4 * l) = acc;
    }
    __syncthreads();  // barrier 4: partials complete

    {
      float s = pp_f[t] + pp_f[256 + t] + pp_f[512 + t] + pp_f[768 + t];
      out[(size_t)b0 * 256 + t] = s > 0.f ? s : (__expf(s) - 1.f);
    }
  }

  if (!has2) return;

  __syncthreads();  // barrier 5: iter0 pp reads done; all regions reusable

  // ---------------- iteration 1 (b1) ----------------
  STAGE_V();            // alpha/pp overlay destroyed v — restage (L2-hot)
  PACK_S(Xi4b, xjB);    // xjB already in flight/arrived

  {
    {
      const int r16 = l & 15, q = l >> 4;
      const unsigned* arow = s_pk + (w * 16 + r16) * 132;
      const unsigned* brow = v_pk + (r16 & 7) * 132;
      f32x4 acc = {0.f, 0.f, 0.f, 0.f};
#pragma unroll
      for (int step = 0; step < 8; ++step) {
        bf16x8 af = *(const bf16x8*)(arow + step * 16 + q * 4);
        bf16x8 bfv = *(const bf16x8*)(brow + step * 16 + q * 4);
        acc = __builtin_amdgcn_mfma_f32_16x16x32_bf16(af, bfv, acc, 0, 0, 0);
      }
      if (r16 < 8) {
#pragma unroll
        for (int j = 0; j < 4; ++j) {
          float ev = acc[j];
          ev = ev >= 0.f ? ev : 0.2f * ev;
          e_f[(w * 16 + q * 4 + j) * 9 + r16] = ev;
        }
      }
    }
    __syncthreads();  // barrier 1'

    float m = -3.4e38f;
#pragma unroll
    for (int q = 0; q < 8; ++q) m = fmaxf(m, e_f[(g * 8 + q) * 9 + h]);
    m = fmaxf(m, __shfl_xor(m, 8, 64));
    m = fmaxf(m, __shfl_xor(m, 16, 64));
    m = fmaxf(m, __shfl_xor(m, 32, 64));
    float ssum = 0.f;
#pragma unroll
    for (int q = 0; q < 8; ++q) ssum += __expf(e_f[(g * 8 + q) * 9 + h] - m);
    ssum += __shfl_xor(ssum, 8, 64);
    ssum += __shfl_xor(ssum, 16, 64);
    ssum += __shfl_xor(ssum, 32, 64);
    float rinv = 1.f / ssum;
#pragma unroll
    for (int pp = 0; pp < 2; ++pp) {
      int n = w * 16 + g + 8 * pp;
      alpha_f[n * 8 + h] = __expf(e_f[n * 9 + h] - m) * rinv;
    }

    float4 acc4[8];
#pragma unroll
    for (int hh = 0; hh < 8; ++hh) acc4[hh] = make_float4(0.f, 0.f, 0.f, 0.f);
#pragma unroll
    for (int i = 0; i < 16; ++i) {
      int n = w * 16 + i;
      float4 a0 = *(const float4*)(alpha_f + n * 8);
      float4 a1 = *(const float4*)(alpha_f + n * 8 + 4);
      float al[8] = {a0.x, a0.y, a0.z, a0.w, a1.x, a1.y, a1.z, a1.w};
      float4 x = xjB[i];
#pragma unroll
      for (int hh = 0; hh < 8; ++hh) {
        acc4[hh].x += al[hh] * x.x;
        acc4[hh].y += al[hh] * x.y;
        acc4[hh].z += al[hh] * x.z;
        acc4[hh].w += al[hh] * x.w;
      }
    }
#pragma unroll
    for (int hh = 0; hh < 8; ++hh)
      *(float4*)(yp_f + (w * 8 + hh) * 260 + 4 * l) = acc4[hh];
    __syncthreads();  // barrier 2'

#pragma unroll
    for (int c = 0; c < 2; ++c) {
      int id = t + c * 256;
      int row = id >> 6, col = (id & 63) * 4;
      float* p = yp_f + row * 260 + col;
      float4 s0 = *(float4*)p;
      float4 s1 = *(float4*)(p + 2080);
      float4 s2 = *(float4*)(p + 4160);
      float4 s3 = *(float4*)(p + 6240);
      s0.x += s1.x + s2.x + s3.x;
      s0.y += s1.y + s2.y + s3.y;
      s0.z += s1.z + s2.z + s3.z;
      s0.w += s1.w + s2.w + s3.w;
      *(float4*)p = s0;
    }
    __syncthreads();  // barrier 3'

    {
      const float* ypb = yp_f + g * 260;
      const float4* W4 = (const float4*)W;
      float4 acc = make_float4(0.f, 0.f, 0.f, 0.f);
      int k0 = w * 64;
#pragma unroll 8
      for (int kc = 0; kc < 16; ++kc) {
        int k = k0 + kc * 4;
        float4 yv = *(const float4*)(ypb + k);
        float4 w0 = W4[(k + 0) * 64 + l];
        float4 w1 = W4[(k + 1) * 64 + l];
        float4 w2 = W4[(k + 2) * 64 + l];
        float4 w3 = W4[(k + 3) * 64 + l];
        acc.x += yv.x * w0.x + yv.y * w1.x + yv.z * w2.x + yv.w * w3.x;
        acc.y += yv.x * w0.y + yv.y * w1.y + yv.z * w2.y + yv.w * w3.y;
        acc.z += yv.x * w0.z + yv.y * w1.z + yv.z * w2.z + yv.w * w3.z;
        acc.w += yv.x * w0.w + yv.y * w1.w + yv.z * w2.w + yv.w * w3.w;
      }
      *(float4*)(pp_f + w * 256 + 4 * l) = acc;
    }
    __syncthreads();  // barrier 4'

    {
      float s = pp_f[t] + pp_f[256 + t] + pp_f[512 + t] + pp_f[768 + t];
      out[(size_t)b1 * 256 + t] = s > 0.f ? s : (__expf(s) - 1.f);
    }
  }
}

extern "C" void kernel_launch(void* const* d_in, const int* in_sizes, int n_in,
                              void* d_out, int out_size, void* d_ws, size_t ws_size,
                              hipStream_t stream) {
  const float* Xi = (const float*)d_in[0];
  const float* Xj = (const float*)d_in[1];
  const float* W = (const float*)d_in[2];
  const float* Watt = (const float*)d_in[3];
  float* out = (float*)d_out;
  float* V = (float*)d_ws;  // 2048 floats
  int B = in_sizes[0] / (NN * IND);
  precompute_v<<<(IND * NH + 255) / 256, 256, 0, stream>>>(W, Watt, V);
  int grid = (B + 1) / 2;
  gat_fused<<<grid, 256, 0, stream>>>(Xi, Xj, W, V, out, B);
}

// Round 6
// 303.809 us; speedup vs baseline: 1.0133x; 1.0133x over previous
//
#include <hip/hip_runtime.h>

#define NN 64
#define IND 256
#define NH 8
#define OD 32

typedef __attribute__((ext_vector_type(8))) short bf16x8;
typedef __attribute__((ext_vector_type(4))) float f32x4;

__device__ __forceinline__ unsigned f2bf(float f) {
  unsigned u = __float_as_uint(f);
  return (u + (((u >> 16) & 1u) + 0x7fffu)) >> 16;  // RNE
}

// V[h][k] = sum_d W[k, h*32+d] * Watt[h, d]   (8 x 256)
__global__ __launch_bounds__(256) void precompute_v(
    const float* __restrict__ W, const float* __restrict__ Watt, float* __restrict__ V) {
  int tid = blockIdx.x * 256 + threadIdx.x;
  if (tid >= IND * NH) return;
  int h = tid >> 8, k = tid & 255;
  float acc = 0.f;
#pragma unroll
  for (int d = 0; d < OD; ++d) acc += W[k * 256 + h * OD + d] * Watt[h * OD + d];
  V[h * 256 + k] = acc;
}

// LDS layout (bytes) — 23424 total -> 6 blocks/CU if VGPR <= 85:
//  [0,     16896)  s bf16: 4 waves x [16 rows][66 words] (k-chunked, 128 cols at a
//                  time, chunk 1 overwrites chunk 0; row stride 66w = 2-bank shift)
//                  overlay post-barrier-1: yp float [4 wavepart][4 heads][260] (16640)
//  [16896, 21120)  v bf16 [8][132 words] (4224)
//                  overlay post-phase-C:  alpha was here first (2048), then pp [8][132] (4224)
//  [21120, 23424)  e float [64][9] (2304; stride 9 kills 8-way conflict)
#define V_OFF 16896
#define E_OFF 21120
#define SMEM_BYTES 23424

// NOTE: plain launch bounds. Measured: (256,3)->cap 84 / (256,4)->cap 64 => spill
// with big live sets. Here the live set is small by design (no persistent xj),
// target <=85 VGPR for 6 waves/SIMD.
__global__ __launch_bounds__(256) void gat_fused(
    const float* __restrict__ Xi, const float* __restrict__ Xj,
    const float* __restrict__ W, const float* __restrict__ V,
    float* __restrict__ out) {
  __shared__ __align__(16) unsigned char smem[SMEM_BYTES];
  unsigned* s_w = (unsigned*)smem;
  unsigned* v_pk = (unsigned*)(smem + V_OFF);
  float* e_f = (float*)(smem + E_OFF);
  float* alpha_f = (float*)(smem + V_OFF);  // overlay: valid after barrier 1 (v dead)
  float* pp_f = (float*)(smem + V_OFF);     // overlay: valid after barrier 2 (alpha dead)
  float* yp_f = (float*)smem;               // overlay: valid after barrier 1 (s dead)

  const int t = threadIdx.x;
  const int b = blockIdx.x;
  const int w = t >> 6, l = t & 63;
  const int g = l >> 3, h = l & 7;
  const int fq = l >> 4, r16 = l & 15;      // MFMA fragment coords

  // wave w owns rows [16w, 16w+16) end-to-end
  const float4* Xi4 = (const float4*)Xi + (size_t)b * (NN * IND / 4);
  const float4* Xj4 = (const float4*)Xj + (size_t)b * (NN * IND / 4);
  unsigned* ws = s_w + w * 1056;            // wave's private 16x66-word s region

  // stage V into LDS as bf16 [8][132w] — redundantly per wave (identical values)
  {
    const float4* V4 = (const float4*)V;
#pragma unroll
    for (int r = 0; r < 8; ++r) {
      float4 vv = V4[r * 64 + l];
      unsigned p0 = f2bf(vv.x) | (f2bf(vv.y) << 16);
      unsigned p1 = f2bf(vv.z) | (f2bf(vv.w) << 16);
      *(uint2*)(v_pk + r * 132 + 2 * l) = make_uint2(p0, p1);
    }
  }

  // Phase A+B fused, k-chunked: per chunk c (128 cols), stream xi+xj in row-pair
  // loads (no persistent registers), pack s = bf16(xi+xj) into the wave's private
  // region, MFMA-accumulate. Chunk 1 overwrites chunk 0's region: same-wave DS
  // ordering + sched_barrier(0) makes the WAR safe (intra-wave, no __syncthreads).
  f32x4 acc = {0.f, 0.f, 0.f, 0.f};
#pragma unroll
  for (int c = 0; c < 2; ++c) {
#pragma unroll
    for (int bq = 0; bq < 2; ++bq) {
      float4 xi[4], xj[4];
#pragma unroll
      for (int p = 0; p < 4; ++p) {
        int pr = bq * 4 + p;  // row pair 0..7
        int f4 = (w * 16 + 2 * pr + (l >> 5)) * 64 + 32 * c + (l & 31);
        xi[p] = Xi4[f4];
        xj[p] = Xj4[f4];
      }
#pragma unroll
      for (int p = 0; p < 4; ++p) {
        int pr = bq * 4 + p;
        int row = 2 * pr + (l >> 5);
        float4 a = xj[p], ci = xi[p];
        unsigned p0 = f2bf(a.x + ci.x) | (f2bf(a.y + ci.y) << 16);
        unsigned p1 = f2bf(a.z + ci.z) | (f2bf(a.w + ci.w) << 16);
        *(uint2*)(ws + row * 66 + 2 * (l & 31)) = make_uint2(p0, p1);
      }
    }
    // MFMA this chunk: 4 K-steps of 32
#pragma unroll
    for (int j = 0; j < 4; ++j) {
      bf16x8 af = *(const bf16x8*)(ws + r16 * 66 + 16 * j + 4 * fq);
      bf16x8 bv = *(const bf16x8*)(v_pk + (r16 & 7) * 132 + 64 * c + 16 * j + 4 * fq);
      acc = __builtin_amdgcn_mfma_f32_16x16x32_bf16(af, bv, acc, 0, 0, 0);
    }
    if (c == 0) __builtin_amdgcn_sched_barrier(0);  // pin chunk1 writes after chunk0 reads
  }
  {
    if (r16 < 8) {
#pragma unroll
      for (int j = 0; j < 4; ++j) {
        float ev = acc[j];
        ev = ev >= 0.f ? ev : 0.2f * ev;              // leakyReLU
        e_f[(w * 16 + fq * 4 + j) * 9 + r16] = ev;    // row=(l>>4)*4+j, col=l&15
      }
    }
  }
  __syncthreads();  // barrier 1: e complete; s and v globally dead

  // softmax over n per h: redundantly per wave (butterfly over 8 lane-groups)
  float m = -3.4e38f;
#pragma unroll
  for (int q = 0; q < 8; ++q) m = fmaxf(m, e_f[(g * 8 + q) * 9 + h]);
  m = fmaxf(m, __shfl_xor(m, 8, 64));
  m = fmaxf(m, __shfl_xor(m, 16, 64));
  m = fmaxf(m, __shfl_xor(m, 32, 64));
  float ssum = 0.f;
#pragma unroll
  for (int q = 0; q < 8; ++q) ssum += __expf(e_f[(g * 8 + q) * 9 + h] - m);
  ssum += __shfl_xor(ssum, 8, 64);
  ssum += __shfl_xor(ssum, 16, 64);
  ssum += __shfl_xor(ssum, 32, 64);
  float rinv = 1.f / ssum;

  // alpha for own rows; consumed only by this wave's Phase C (no barrier)
#pragma unroll
  for (int pp = 0; pp < 2; ++pp) {
    int n = w * 16 + g + 8 * pp;
    alpha_f[n * 8 + h] = __expf(e_f[n * 9 + h] - m) * rinv;
  }

  // Phase C: re-load Xj (L3-hot: first read was ~20-30us ago, inside the L3
  // reuse window) streamed in 4-row groups; alpha reads wave-local broadcasts.
  float4 acc4[8];
#pragma unroll
  for (int hh = 0; hh < 8; ++hh) acc4[hh] = make_float4(0.f, 0.f, 0.f, 0.f);
#pragma unroll
  for (int gr = 0; gr < 4; ++gr) {
    float4 xr[4];
#pragma unroll
    for (int i2 = 0; i2 < 4; ++i2)
      xr[i2] = Xj4[(w * 16 + 4 * gr + i2) * 64 + l];
#pragma unroll
    for (int i2 = 0; i2 < 4; ++i2) {
      int n = w * 16 + 4 * gr + i2;
      float4 a0 = *(const float4*)(alpha_f + n * 8);
      float4 a1 = *(const float4*)(alpha_f + n * 8 + 4);
      float al[8] = {a0.x, a0.y, a0.z, a0.w, a1.x, a1.y, a1.z, a1.w};
      float4 x = xr[i2];
#pragma unroll
      for (int hh = 0; hh < 8; ++hh) {
        acc4[hh].x += al[hh] * x.x;
        acc4[hh].y += al[hh] * x.y;
        acc4[hh].z += al[hh] * x.z;
        acc4[hh].w += al[hh] * x.w;
      }
    }
  }

  // Epilogue in 2 head-passes (halves yp LDS): pass P covers heads 4P..4P+3,
  // out cols [128P, 128P+128). Thread (q4=t&31, kp=t>>5): col-quad 4*q4, k in
  // [32kp, 32kp+32). yp 4-partial reads: 2 distinct addrs per bank group = free.
  {
    const int q4 = t & 31, kp = t >> 5;
#pragma unroll
    for (int P = 0; P < 2; ++P) {
#pragma unroll
      for (int p = 0; p < 4; ++p)
        *(float4*)(yp_f + (w * 4 + p) * 260 + 4 * l) = acc4[4 * P + p];
      __syncthreads();  // yp pass-P complete

      {
        int hh = q4 >> 3;
        const float* yb = yp_f + hh * 260 + 32 * kp;
        const float4* W4 = (const float4*)W;  // W4[k*64 + quad] = W[k][4quad..+3]
        float4 a = make_float4(0.f, 0.f, 0.f, 0.f);
#pragma unroll
        for (int j = 0; j < 8; ++j) {
          float4 y0 = *(const float4*)(yb + 4 * j);
          float4 y1 = *(const float4*)(yb + 1040 + 4 * j);
          float4 y2 = *(const float4*)(yb + 2080 + 4 * j);
          float4 y3 = *(const float4*)(yb + 3120 + 4 * j);
          float4 yq;
          yq.x = y0.x + y1.x + y2.x + y3.x;
          yq.y = y0.y + y1.y + y2.y + y3.y;
          yq.z = y0.z + y1.z + y2.z + y3.z;
          yq.w = y0.w + y1.w + y2.w + y3.w;
          int k = 32 * kp + 4 * j;
          float4 w0 = W4[(k + 0) * 64 + 32 * P + q4];
          float4 w1 = W4[(k + 1) * 64 + 32 * P + q4];
          float4 w2 = W4[(k + 2) * 64 + 32 * P + q4];
          float4 w3 = W4[(k + 3) * 64 + 32 * P + q4];
          a.x += yq.x * w0.x + yq.y * w1.x + yq.z * w2.x + yq.w * w3.x;
          a.y += yq.x * w0.y + yq.y * w1.y + yq.z * w2.y + yq.w * w3.y;
          a.z += yq.x * w0.z + yq.y * w1.z + yq.z * w2.z + yq.w * w3.z;
          a.w += yq.x * w0.w + yq.y * w1.w + yq.z * w2.w + yq.w * w3.w;
        }
        *(float4*)(pp_f + kp * 132 + 4 * q4) = a;
      }
      __syncthreads();  // pp pass-P complete

      if (t < 128) {
        float s = 0.f;
#pragma unroll
        for (int k8 = 0; k8 < 8; ++k8) s += pp_f[k8 * 132 + t];
        out[(size_t)b * 256 + 128 * P + t] = s > 0.f ? s : (__expf(s) - 1.f);
      }
      if (P == 0) __syncthreads();  // out reads of pp done; yp/pp reusable for pass 1
    }
  }
}

extern "C" void kernel_launch(void* const* d_in, const int* in_sizes, int n_in,
                              void* d_out, int out_size, void* d_ws, size_t ws_size,
                              hipStream_t stream) {
  const float* Xi = (const float*)d_in[0];
  const float* Xj = (const float*)d_in[1];
  const float* W = (const float*)d_in[2];
  const float* Watt = (const float*)d_in[3];
  float* out = (float*)d_out;
  float* V = (float*)d_ws;  // 2048 floats
  int B = in_sizes[0] / (NN * IND);
  precompute_v<<<(IND * NH + 255) / 256, 256, 0, stream>>>(W, Watt, V);
  gat_fused<<<B, 256, 0, stream>>>(Xi, Xj, W, V, out);
}